// Round 9
// baseline (159.020 us; speedup 1.0000x reference)
//
#include <hip/hip_runtime.h>

// out = softmax(q @ keys^T) @ keys, fused flash-style, round 9.
// 32x32x16 MFMAs halve LDS bytes/FLOP: 32 q-rows/wave, 4 waves/block,
// grid 256 (1 block/CU, 1 wave/SIMD, VGPR ~310). Score S^T = mfma32(K, q)
// puts a full q-row (16 of 32 keys + partner lane) per lane; KT image is
// key-permuted by sigma so score-D reg order == PV A-frag order (no
// shuffles). Kh swizzle c^(kk&7), KT swizzle s^((d>>1)&3): both 2-way.
// Double-buffered DMA via global_load_lds, 1 barrier/tile.

typedef _Float16 f16;
typedef f16 f16x8 __attribute__((ext_vector_type(8)));
typedef float f32x16 __attribute__((ext_vector_type(16)));

#define NT 64
#define MF(a, b, c) __builtin_amdgcn_mfma_f32_32x32x16_f16(a, b, c, 0, 0, 0)

__device__ __forceinline__ void gl_lds16(const f16* g, f16* l) {
  __builtin_amdgcn_global_load_lds(
      (const __attribute__((address_space(1))) void*)g,
      (__attribute__((address_space(3))) void*)l, 16, 0, 0);
}

// ---- pre-kernel: swizzled per-32-key-tile images (grid 256 x 256) ----
// ws f16: [0,524288): Kh images (64 x 8192); [524288,1048576): KT images.
__global__ void prep_kernel(const float* __restrict__ keys, f16* __restrict__ ws) {
  int i = blockIdx.x * 256 + threadIdx.x;  // 0..65535
  int t = i >> 10;
  {  // Kh: key kk (0..31), 16B-chunk c (0..31); slot = c ^ (kk&7)
    int kk = (i >> 5) & 31, c = i & 31;
    const float* src = keys + (((t << 5) + kk) << 8) + (c << 3);
    f16x8 v;
    #pragma unroll
    for (int e = 0; e < 8; ++e) v[e] = (f16)src[e];
    *(f16x8*)&ws[t * 8192 + kk * 256 + ((c ^ (kk & 7)) << 3)] = v;
  }
  {  // KT: dim d (0..255), k-slot s (0..3) holding phys keys sigma(s*8+j);
     // image slot = s ^ ((d>>1)&3)
    int d = (i >> 2) & 255, s = i & 3;
    f16x8 v;
    #pragma unroll
    for (int j = 0; j < 8; ++j) {
      int k = s * 8 + j;
      int sig = 4 * ((k >> 3) & 1) + (k & 3) + 8 * (2 * (k >> 4) + ((k >> 2) & 1));
      v[j] = (f16)keys[(((t << 5) + sig) << 8) + d];
    }
    *(f16x8*)&ws[524288 + t * 8192 + (d << 5) + ((s ^ ((d >> 1) & 3)) << 3)] = v;
  }
}

__global__ __launch_bounds__(256, 1)
void mtr_kernel(const f16* __restrict__ ws,
                const float* __restrict__ query,
                float* __restrict__ out) {
  __shared__ f16 KH[2][8192];   // 32 KB (dbuf)
  __shared__ f16 KT[2][8192];   // 32 KB (dbuf)

  const int tid  = threadIdx.x;
  const int lane = tid & 63;
  const int wave = tid >> 6;   // 0..3, owns q-rows [wave*32, wave*32+32)
  const int h    = lane >> 5;  // 0..1 (k-half)
  const int dl   = lane & 31;

  const int nbase  = blockIdx.x * 128;  // grid 256
  const int b      = nbase >> 12;
  const int hwbase = nbase & 4095;

  // ---- q fragments: B-operand of score mfma32. Lane holds
  // q[col = dl][k = c*16 + h*8 + j], hi/lo fp16 split (q exact).
  f16x8 qh[16], ql[16];
  {
    const float* qb = query + ((size_t)b << 20) + hwbase + wave * 32 + dl;
    #pragma unroll
    for (int c = 0; c < 16; ++c)
      #pragma unroll
      for (int j = 0; j < 8; ++j) {
        int d = c * 16 + h * 8 + j;
        float v = qb[(size_t)d << 12];
        f16 hh = (f16)v;
        qh[c][j] = hh;
        ql[c][j] = (f16)(v - (float)hh);
      }
  }

  f32x16 O[8];
  #pragma unroll
  for (int i = 0; i < 8; ++i) O[i] = (f32x16)(0.f);
  float m_run = -INFINITY, l_run = 0.f;

  const int xK = dl & 7;          // Kh read xor (matches image)
  const int xT = (dl >> 1) & 3;   // KT read xor
  const int rowK = dl * 256;      // Kh row base (f16), key = dl
  // DMA duty: wave 0,1 -> KH halves; wave 2,3 -> KT halves (8 x 1KB each)
  const f16* wsrc = ws + ((wave >> 1) ? 524288 : 0) + ((wave & 1) << 12) + lane * 8;
  const int dsth = (wave & 1) << 12;

  {  // prologue: stage tile 0 into buffer 0
    f16* dstb = ((wave >> 1) ? &KT[0][0] : &KH[0][0]) + dsth;
    #pragma unroll
    for (int i = 0; i < 8; ++i) gl_lds16(wsrc + i * 512, dstb + i * 512);
  }
  __syncthreads();

  for (int t = 0; t < NT; ++t) {
    const int cur = t & 1;

    // ---- issue next-tile DMA (drained by end-of-tile barrier)
    if (t + 1 < NT) {
      f16* dstb = ((wave >> 1) ? &KT[cur ^ 1][0] : &KH[cur ^ 1][0]) + dsth;
      const f16* s = wsrc + (t + 1) * 8192;
      #pragma unroll
      for (int i = 0; i < 8; ++i) gl_lds16(s + i * 512, dstb + i * 512);
    }

    const f16* KHc = &KH[cur][0];
    const f16* KTc = &KT[cur][0];

    // ---- score: S^T[32 keys][32 q], A = K rows (key = dl), B = q regs
    f32x16 sc = (f32x16)(0.f);
    #pragma unroll
    for (int c = 0; c < 16; ++c) {
      f16x8 a = *(const f16x8*)&KHc[rowK + ((((c << 1) | h) ^ xK) << 3)];
      sc = MF(a, qh[c], sc);
      sc = MF(a, ql[c], sc);
    }
    // lane holds S[phys key (r&3)+8*(r>>2)+4h][q = dl], r = 0..15

    // ---- online softmax for q-row dl (2 lanes per row: dl, dl+32)
    float tmax = sc[0];
    #pragma unroll
    for (int r = 1; r < 16; ++r) tmax = fmaxf(tmax, sc[r]);
    tmax = fmaxf(tmax, __shfl_xor(tmax, 32));

    if (__any(tmax > m_run + 8.f)) {  // defer-max (T13)
      float m_new = fmaxf(m_run, tmax);
      float scale = __expf(m_run - m_new);
      l_run *= scale;
      m_run = m_new;
      float fr[16];
      #pragma unroll
      for (int r = 0; r < 16; ++r)
        fr[r] = __shfl(scale, (r & 3) + 8 * (r >> 2) + 4 * h);
      #pragma unroll
      for (int dt = 0; dt < 8; ++dt)
        #pragma unroll
        for (int r = 0; r < 16; ++r) O[dt][r] *= fr[r];
    }

    float e[16], ts = 0.f;
    #pragma unroll
    for (int r = 0; r < 16; ++r) {
      e[r] = __expf(sc[r] - m_run);
      ts += e[r];
    }
    ts += __shfl_xor(ts, 32);
    l_run += ts;

    // PV A-frags: sigma-permuted KT makes reg order == A order
    f16x8 pa0, pa1;
    #pragma unroll
    for (int j = 0; j < 8; ++j) {
      pa0[j] = (f16)e[j];
      pa1[j] = (f16)e[8 + j];
    }

    // ---- PV: O[q][d] += P @ K, B-frags from KT image
    #pragma unroll
    for (int dt = 0; dt < 8; ++dt) {
      int rbase = dt * 1024 + dl * 32;
      f16x8 b0 = *(const f16x8*)&KTc[rbase + ((h ^ xT) << 3)];
      f16x8 b1 = *(const f16x8*)&KTc[rbase + (((2 + h) ^ xT) << 3)];
      O[dt] = MF(pa0, b0, O[dt]);
      O[dt] = MF(pa1, b1, O[dt]);
    }

    __syncthreads();  // next-tile images complete; buffers swap
  }

  // ---- epilogue: normalize, store NCHW (float4 runs over w)
  float invl = 1.f / l_run;  // valid for q = dl (both halves)
  float nf[16];
  #pragma unroll
  for (int r = 0; r < 16; ++r)
    nf[r] = __shfl(invl, (r & 3) + 8 * (r >> 2) + 4 * h);
  #pragma unroll
  for (int dt = 0; dt < 8; ++dt) {
    int d = dt * 32 + dl;
    float* op = out + ((size_t)b << 20) + ((size_t)d << 12) + hwbase + wave * 32 + 4 * h;
    #pragma unroll
    for (int u = 0; u < 4; ++u) {
      float4 w4;
      w4.x = O[dt][4 * u + 0] * nf[4 * u + 0];
      w4.y = O[dt][4 * u + 1] * nf[4 * u + 1];
      w4.z = O[dt][4 * u + 2] * nf[4 * u + 2];
      w4.w = O[dt][4 * u + 3] * nf[4 * u + 3];
      *(float4*)(op + 8 * u) = w4;
    }
  }
}

extern "C" void kernel_launch(void* const* d_in, const int* in_sizes, int n_in,
                              void* d_out, int out_size, void* d_ws, size_t ws_size,
                              hipStream_t stream) {
  const float* keys  = (const float*)d_in[0];
  const float* query = (const float*)d_in[1];
  float* out = (float*)d_out;
  f16* ws = (f16*)d_ws;
  hipLaunchKernelGGL(prep_kernel, dim3(256), dim3(256), 0, stream, keys, ws);
  hipLaunchKernelGGL(mtr_kernel, dim3(256), dim3(256), 0, stream, ws, query, out);
}

// Round 10
// 128.663 us; speedup vs baseline: 1.2359x; 1.2359x over previous
//
#include <hip/hip_runtime.h>

// out = softmax(q @ keys^T) @ keys, fused flash-style, round 10.
// = r8 (best: 125us; 16 q/wave, 2048 waves, pre-swizzled ws images, DMA
//   staging, key-permuted x32 score + x32 PV, 2-way bank swizzles) plus:
//   (1) log2(e) folded into Kh image -> softmax is raw exp2f (THR=11 log2),
//   (2) s_setprio(1) around MFMA clusters (T5; phase-diverse blocks),
//   (3) #pragma unroll 2 on tile loop (both buffers' LDS addrs hoisted).

typedef _Float16 f16;
typedef f16 f16x8 __attribute__((ext_vector_type(8)));
typedef float f32x4 __attribute__((ext_vector_type(4)));

#define NT 64
#define MF32(a, b, c) __builtin_amdgcn_mfma_f32_16x16x32_f16(a, b, c, 0, 0, 0)

__device__ __forceinline__ void gl_lds16(const f16* g, f16* l) {
  __builtin_amdgcn_global_load_lds(
      (const __attribute__((address_space(1))) void*)g,
      (__attribute__((address_space(3))) void*)l, 16, 0, 0);
}

// ---- pre-kernel: build swizzled per-tile images (grid 256 x 256) ----
__global__ void prep_kernel(const float* __restrict__ keys, f16* __restrict__ ws) {
  int i = blockIdx.x * 256 + threadIdx.x;  // 0..65535
  int t = i >> 10;
  {  // Kh image (scaled by log2e): key kk, chunk c; slot = c ^ xk
    int kk = (i >> 5) & 31, c = i & 31;
    const float* src = keys + (((t << 5) + kk) << 8) + (c << 3);
    f16x8 v;
    #pragma unroll
    for (int e = 0; e < 8; ++e) v[e] = (f16)(src[e] * 1.4426950408889634f);
    int xk = (kk & 3) | (((kk >> 3) & 1) << 2);
    *(f16x8*)&ws[t * 8192 + kk * 256 + ((c ^ xk) << 3)] = v;
  }
  {  // KT image (unscaled): dim d, key-group g, swizzled slot
    int d = (i >> 2) & 255, g = i & 3;
    const float* src = keys + (((t << 5) + (g << 3)) << 8) + d;
    f16x8 v;
    #pragma unroll
    for (int j = 0; j < 8; ++j) v[j] = (f16)src[j << 8];
    *(f16x8*)&ws[524288 + t * 8192 + (d >> 1) * 64 +
                 (((((d & 1) << 2) | g) ^ ((d >> 1) & 7)) << 3)] = v;
  }
}

__global__ __launch_bounds__(256, 2)
void mtr_kernel(const f16* __restrict__ ws,
                const float* __restrict__ query,
                float* __restrict__ out) {
  __shared__ f16 KB[2][8192];   // 32 KB: Kh images (dbuf)
  __shared__ f16 KT[2][8192];   // 32 KB: KT images (dbuf)

  const int tid  = threadIdx.x;
  const int lane = tid & 63;
  const int wave = tid >> 6;   // 0..3, owns q-rows [wave*16, wave*16+16)
  const int g    = lane >> 4;  // 0..3
  const int qr   = lane & 15;

  const int nbase  = blockIdx.x * 64;
  const int b      = nbase >> 12;
  const int hwbase = nbase & 4095;

  // ---- q fragments, hi/lo fp16 split (q exact). Score B-layout:
  // lane holds q[row=qr][d = dt*32 + g*8 + j]
  f16x8 qh[8], ql[8];
  {
    const float* qb = query + ((size_t)b << 20) + hwbase + wave * 16 + qr;
    #pragma unroll
    for (int dt = 0; dt < 8; ++dt)
      #pragma unroll
      for (int j = 0; j < 8; ++j) {
        int c = dt * 32 + g * 8 + j;
        float v = qb[(size_t)c << 12];
        f16 h = (f16)v;
        qh[dt][j] = h;
        ql[dt][j] = (f16)(v - (float)h);
      }
  }

  f32x4 O[16];
  #pragma unroll
  for (int i = 0; i < 16; ++i) O[i] = (f32x4){0.f, 0.f, 0.f, 0.f};
  float m_run = -INFINITY, l_run = 0.f;  // m in log2 units

  // score A-rows: key-permuted phys key = 8*(qr>>2) + 4*kt + (qr&3)
  const int rb0 = (((qr >> 2) << 3) + (qr & 3)) << 8;  // row pk0 (512B rows)
  const int rb1 = rb0 + 1024;                          // pk0 + 4
  const int xs  = (qr & 3) | (((qr >> 2) & 1) << 2);   // image xor, both rows
  // PV read row-base (f16 units) within each dtile's 1KB
  const int rbT = ((qr >> 1) << 6) + (((((qr & 1) << 2) | g) ^ ((qr >> 1) & 7)) << 3);

  // ---- DMA duty: waves 0,1 -> KB halves; waves 2,3 -> KT halves.
  const f16* wsrc = ws + ((wave >> 1) ? 524288 : 0) + ((wave & 1) << 12) + lane * 8;
  const int dst_half = (wave & 1) << 12;  // f16 offset of this wave's half

  // prologue: stage tile 0 into buffer 0
  {
    f16* dstb = ((wave >> 1) ? &KT[0][0] : &KB[0][0]) + dst_half;
    #pragma unroll
    for (int i = 0; i < 8; ++i) gl_lds16(wsrc + i * 512, dstb + i * 512);
  }
  __syncthreads();

  #pragma unroll 2
  for (int t = 0; t < NT; ++t) {
    const int cur = t & 1;

    // ---- issue next-tile DMA into other buffer (drained by end barrier)
    if (t + 1 < NT) {
      f16* dstb = ((wave >> 1) ? &KT[cur ^ 1][0] : &KB[cur ^ 1][0]) + dst_half;
      const f16* s = wsrc + (t + 1) * 8192;
      #pragma unroll
      for (int i = 0; i < 8; ++i) gl_lds16(s + i * 512, dstb + i * 512);
    }

    // ---- score: S^T[key'][q] in log2 units (K pre-scaled by log2e)
    const f16* KBc = &KB[cur][0];
    f32x4 s0 = (f32x4){0.f, 0.f, 0.f, 0.f};
    f32x4 s1 = (f32x4){0.f, 0.f, 0.f, 0.f};
    __builtin_amdgcn_s_setprio(1);
    #pragma unroll
    for (int dt = 0; dt < 8; ++dt) {
      int c = (dt << 2) + g;
      f16x8 a0 = *(const f16x8*)&KBc[rb0 + ((c ^ xs) << 3)];
      f16x8 a1 = *(const f16x8*)&KBc[rb1 + ((c ^ xs) << 3)];
      s0 = MF32(a0, qh[dt], s0); s0 = MF32(a0, ql[dt], s0);
      s1 = MF32(a1, qh[dt], s1); s1 = MF32(a1, ql[dt], s1);
    }
    __builtin_amdgcn_s_setprio(0);
    // lane holds S[q=qr][key 8g+i] (s0) and 8g+4+i (s1)

    // ---- online softmax (row = qr); defer-max (T13), log2 domain
    float tmax = fmaxf(fmaxf(fmaxf(s0[0], s0[1]), fmaxf(s0[2], s0[3])),
                       fmaxf(fmaxf(s1[0], s1[1]), fmaxf(s1[2], s1[3])));
    tmax = fmaxf(tmax, __shfl_xor(tmax, 16));
    tmax = fmaxf(tmax, __shfl_xor(tmax, 32));

    if (__any(tmax > m_run + 11.f)) {
      float m_new = fmaxf(m_run, tmax);
      float sc = exp2f(m_run - m_new);
      l_run *= sc;
      m_run = m_new;
      float osc0 = __shfl(sc, g * 4 + 0);
      float osc1 = __shfl(sc, g * 4 + 1);
      float osc2 = __shfl(sc, g * 4 + 2);
      float osc3 = __shfl(sc, g * 4 + 3);
      #pragma unroll
      for (int dtile = 0; dtile < 16; ++dtile) {
        O[dtile][0] *= osc0; O[dtile][1] *= osc1;
        O[dtile][2] *= osc2; O[dtile][3] *= osc3;
      }
    }

    float ts = 0.f;
    f16x8 pa;  // x32 PV A-frag: k = g*8+j -> phys key 8g+j
    #pragma unroll
    for (int i = 0; i < 4; ++i) {
      float e0 = exp2f(s0[i] - m_run);  // bounded by 2^11
      float e1 = exp2f(s1[i] - m_run);
      ts += e0 + e1;
      pa[i] = (f16)e0;
      pa[4 + i] = (f16)e1;
    }
    ts += __shfl_xor(ts, 16);
    ts += __shfl_xor(ts, 32);
    l_run += ts;

    // ---- PV: all-x32, B-frags from KT image (compile-time strides)
    const f16* KTc = &KT[cur][0];
    __builtin_amdgcn_s_setprio(1);
    #pragma unroll
    for (int dtile = 0; dtile < 16; ++dtile) {
      f16x8 vb = *(const f16x8*)&KTc[dtile * 512 + rbT];
      O[dtile] = MF32(pa, vb, O[dtile]);
    }
    __builtin_amdgcn_s_setprio(0);

    __syncthreads();  // next-tile images complete; buffers swap
  }

  // ---- epilogue: normalize by row-sum, store NCHW (float4 over w)
  float n0 = 1.f / __shfl(l_run, g * 4 + 0);
  float n1 = 1.f / __shfl(l_run, g * 4 + 1);
  float n2 = 1.f / __shfl(l_run, g * 4 + 2);
  float n3 = 1.f / __shfl(l_run, g * 4 + 3);
  float* ob = out + ((size_t)b << 20) + hwbase + wave * 16 + g * 4;
  #pragma unroll
  for (int dtile = 0; dtile < 16; ++dtile) {
    int c = dtile * 16 + qr;
    float4 w4;
    w4.x = O[dtile][0] * n0;
    w4.y = O[dtile][1] * n1;
    w4.z = O[dtile][2] * n2;
    w4.w = O[dtile][3] * n3;
    *(float4*)(ob + ((size_t)c << 12)) = w4;
  }
}

extern "C" void kernel_launch(void* const* d_in, const int* in_sizes, int n_in,
                              void* d_out, int out_size, void* d_ws, size_t ws_size,
                              hipStream_t stream) {
  const float* keys  = (const float*)d_in[0];
  const float* query = (const float*)d_in[1];
  float* out = (float*)d_out;
  f16* ws = (f16*)d_ws;
  hipLaunchKernelGGL(prep_kernel, dim3(256), dim3(256), 0, stream, keys, ws);
  hipLaunchKernelGGL(mtr_kernel, dim3(512), dim3(256), 0, stream, ws, query, out);
}

// Round 11
// 112.830 us; speedup vs baseline: 1.4094x; 1.1403x over previous
//
#include <hip/hip_runtime.h>

// out = softmax(q @ keys^T) @ keys, fused flash-style, round 11.
// = r8 (best: 125us) with ONE change: single-term score S = Kh*qh
//   (ql compensation term dropped). Score-phase MFMA chain halves
//   (32 -> 16 MFMAs/wave-tile). Error budget: (K-Kh)*q term (~2.2e-3 rms,
//   already present in r8, absmax 0.031) gains an independent equal-size
//   (Kh)*(q-qh) term -> ~x1.41 score error, predicted absmax ~0.04.
//   Everything else byte-identical to r8.

typedef _Float16 f16;
typedef f16 f16x8 __attribute__((ext_vector_type(8)));
typedef float f32x4 __attribute__((ext_vector_type(4)));

#define NT 64
#define MF32(a, b, c) __builtin_amdgcn_mfma_f32_16x16x32_f16(a, b, c, 0, 0, 0)

__device__ __forceinline__ void gl_lds16(const f16* g, f16* l) {
  __builtin_amdgcn_global_load_lds(
      (const __attribute__((address_space(1))) void*)g,
      (__attribute__((address_space(3))) void*)l, 16, 0, 0);
}

// ---- pre-kernel: build swizzled per-tile images (grid 256 x 256) ----
__global__ void prep_kernel(const float* __restrict__ keys, f16* __restrict__ ws) {
  int i = blockIdx.x * 256 + threadIdx.x;  // 0..65535
  int t = i >> 10;
  {  // Kh image: key kk, chunk c; slot = c ^ ((kk&3)|(((kk>>3)&1)<<2))
    int kk = (i >> 5) & 31, c = i & 31;
    const float* src = keys + (((t << 5) + kk) << 8) + (c << 3);
    f16x8 v;
    #pragma unroll
    for (int e = 0; e < 8; ++e) v[e] = (f16)src[e];
    int xk = (kk & 3) | (((kk >> 3) & 1) << 2);
    *(f16x8*)&ws[t * 8192 + kk * 256 + ((c ^ xk) << 3)] = v;
  }
  {  // KT image: dim d, key-group g (keys g*8..g*8+7 at dim d), swizzled slot
    int d = (i >> 2) & 255, g = i & 3;
    const float* src = keys + (((t << 5) + (g << 3)) << 8) + d;
    f16x8 v;
    #pragma unroll
    for (int j = 0; j < 8; ++j) v[j] = (f16)src[j << 8];
    *(f16x8*)&ws[524288 + t * 8192 + (d >> 1) * 64 +
                 (((((d & 1) << 2) | g) ^ ((d >> 1) & 7)) << 3)] = v;
  }
}

__global__ __launch_bounds__(256, 2)
void mtr_kernel(const f16* __restrict__ ws,
                const float* __restrict__ query,
                float* __restrict__ out) {
  __shared__ f16 KB[2][8192];   // 32 KB: Kh images (dbuf)
  __shared__ f16 KT[2][8192];   // 32 KB: KT images (dbuf)

  const int tid  = threadIdx.x;
  const int lane = tid & 63;
  const int wave = tid >> 6;   // 0..3, owns q-rows [wave*16, wave*16+16)
  const int g    = lane >> 4;  // 0..3
  const int qr   = lane & 15;

  const int nbase  = blockIdx.x * 64;
  const int b      = nbase >> 12;
  const int hwbase = nbase & 4095;

  // ---- q fragments (fp16). Score B-layout: lane holds
  // q[row=qr][d = dt*32 + g*8 + j]
  f16x8 qh[8];
  {
    const float* qb = query + ((size_t)b << 20) + hwbase + wave * 16 + qr;
    #pragma unroll
    for (int dt = 0; dt < 8; ++dt)
      #pragma unroll
      for (int j = 0; j < 8; ++j) {
        int c = dt * 32 + g * 8 + j;
        qh[dt][j] = (f16)qb[(size_t)c << 12];
      }
  }

  f32x4 O[16];
  #pragma unroll
  for (int i = 0; i < 16; ++i) O[i] = (f32x4){0.f, 0.f, 0.f, 0.f};
  float m_run = -INFINITY, l_run = 0.f;

  // score A-rows: key-permuted phys key = 8*(qr>>2) + 4*kt + (qr&3)
  const int rb0 = (((qr >> 2) << 3) + (qr & 3)) << 8;  // row pk0 (512B rows)
  const int rb1 = rb0 + 1024;                          // pk0 + 4
  const int xs  = (qr & 3) | (((qr >> 2) & 1) << 2);   // image xor, both rows
  // PV read row-base (f16 units) within each dtile's 1KB
  const int rbT = ((qr >> 1) << 6) + (((((qr & 1) << 2) | g) ^ ((qr >> 1) & 7)) << 3);

  // ---- DMA duty: waves 0,1 -> KB halves; waves 2,3 -> KT halves.
  const f16* wsrc = ws + ((wave >> 1) ? 524288 : 0) + ((wave & 1) << 12) + lane * 8;
  const int dst_half = (wave & 1) << 12;  // f16 offset of this wave's half

  // prologue: stage tile 0 into buffer 0
  {
    f16* dstb = ((wave >> 1) ? &KT[0][0] : &KB[0][0]) + dst_half;
    #pragma unroll
    for (int i = 0; i < 8; ++i) gl_lds16(wsrc + i * 512, dstb + i * 512);
  }
  __syncthreads();

  for (int t = 0; t < NT; ++t) {
    const int cur = t & 1;

    // ---- issue next-tile DMA into other buffer (drained by end barrier)
    if (t + 1 < NT) {
      f16* dstb = ((wave >> 1) ? &KT[cur ^ 1][0] : &KB[cur ^ 1][0]) + dst_half;
      const f16* s = wsrc + (t + 1) * 8192;
      #pragma unroll
      for (int i = 0; i < 8; ++i) gl_lds16(s + i * 512, dstb + i * 512);
    }

    // ---- score: S^T[key'][q], key-permuted A-rows, single term Kh*qh
    const f16* KBc = &KB[cur][0];
    f32x4 s0 = (f32x4){0.f, 0.f, 0.f, 0.f};
    f32x4 s1 = (f32x4){0.f, 0.f, 0.f, 0.f};
    #pragma unroll
    for (int dt = 0; dt < 8; ++dt) {
      int c = (dt << 2) + g;
      f16x8 a0 = *(const f16x8*)&KBc[rb0 + ((c ^ xs) << 3)];
      f16x8 a1 = *(const f16x8*)&KBc[rb1 + ((c ^ xs) << 3)];
      s0 = MF32(a0, qh[dt], s0);
      s1 = MF32(a1, qh[dt], s1);
    }
    // lane holds S[q=qr][key 8g+i] (s0) and 8g+4+i (s1)

    // ---- online softmax (row = qr); defer-max (T13)
    float tmax = fmaxf(fmaxf(fmaxf(s0[0], s0[1]), fmaxf(s0[2], s0[3])),
                       fmaxf(fmaxf(s1[0], s1[1]), fmaxf(s1[2], s1[3])));
    tmax = fmaxf(tmax, __shfl_xor(tmax, 16));
    tmax = fmaxf(tmax, __shfl_xor(tmax, 32));

    if (__any(tmax > m_run + 8.f)) {
      float m_new = fmaxf(m_run, tmax);
      float sc = __expf(m_run - m_new);
      l_run *= sc;
      m_run = m_new;
      float osc0 = __shfl(sc, g * 4 + 0);
      float osc1 = __shfl(sc, g * 4 + 1);
      float osc2 = __shfl(sc, g * 4 + 2);
      float osc3 = __shfl(sc, g * 4 + 3);
      #pragma unroll
      for (int dtile = 0; dtile < 16; ++dtile) {
        O[dtile][0] *= osc0; O[dtile][1] *= osc1;
        O[dtile][2] *= osc2; O[dtile][3] *= osc3;
      }
    }

    float ts = 0.f;
    f16x8 pa;  // x32 PV A-frag: k = g*8+j -> phys key 8g+j
    #pragma unroll
    for (int i = 0; i < 4; ++i) {
      float e0 = __expf(s0[i] - m_run);
      float e1 = __expf(s1[i] - m_run);
      ts += e0 + e1;
      pa[i] = (f16)e0;
      pa[4 + i] = (f16)e1;
    }
    ts += __shfl_xor(ts, 16);
    ts += __shfl_xor(ts, 32);
    l_run += ts;

    // ---- PV: all-x32, B-frags from KT image (compile-time strides)
    const f16* KTc = &KT[cur][0];
    #pragma unroll
    for (int dtile = 0; dtile < 16; ++dtile) {
      f16x8 vb = *(const f16x8*)&KTc[dtile * 512 + rbT];
      O[dtile] = MF32(pa, vb, O[dtile]);
    }

    __syncthreads();  // next-tile images complete; buffers swap
  }

  // ---- epilogue: normalize by row-sum, store NCHW (float4 over w)
  float n0 = 1.f / __shfl(l_run, g * 4 + 0);
  float n1 = 1.f / __shfl(l_run, g * 4 + 1);
  float n2 = 1.f / __shfl(l_run, g * 4 + 2);
  float n3 = 1.f / __shfl(l_run, g * 4 + 3);
  float* ob = out + ((size_t)b << 20) + hwbase + wave * 16 + g * 4;
  #pragma unroll
  for (int dtile = 0; dtile < 16; ++dtile) {
    int c = dtile * 16 + qr;
    float4 w4;
    w4.x = O[dtile][0] * n0;
    w4.y = O[dtile][1] * n1;
    w4.z = O[dtile][2] * n2;
    w4.w = O[dtile][3] * n3;
    *(float4*)(ob + ((size_t)c << 12)) = w4;
  }
}

extern "C" void kernel_launch(void* const* d_in, const int* in_sizes, int n_in,
                              void* d_out, int out_size, void* d_ws, size_t ws_size,
                              hipStream_t stream) {
  const float* keys  = (const float*)d_in[0];
  const float* query = (const float*)d_in[1];
  float* out = (float*)d_out;
  f16* ws = (f16*)d_ws;
  hipLaunchKernelGGL(prep_kernel, dim3(256), dim3(256), 0, stream, keys, ws);
  hipLaunchKernelGGL(mtr_kernel, dim3(512), dim3(256), 0, stream, ws, query, out);
}

// Round 12
// 104.772 us; speedup vs baseline: 1.5178x; 1.0769x over previous
//
#include <hip/hip_runtime.h>

// out = softmax(q @ keys^T) @ keys, fused flash-style, round 12.
// = r11 (112.8us) with ONE change: softmax common path has ZERO cross-lane
//   ops. Trigger = __any(lanemax > m+8) (semantically identical to row-max
//   test); l_run is a per-lane partial reduced in the epilogue; the 2+2
//   ds_bpermute shuffles per tile (same LDS pipe as the b128 reads!) are
//   gone from the common path. Rescale path (rare) unchanged.

typedef _Float16 f16;
typedef f16 f16x8 __attribute__((ext_vector_type(8)));
typedef float f32x4 __attribute__((ext_vector_type(4)));

#define NT 64
#define MF32(a, b, c) __builtin_amdgcn_mfma_f32_16x16x32_f16(a, b, c, 0, 0, 0)

__device__ __forceinline__ void gl_lds16(const f16* g, f16* l) {
  __builtin_amdgcn_global_load_lds(
      (const __attribute__((address_space(1))) void*)g,
      (__attribute__((address_space(3))) void*)l, 16, 0, 0);
}

// ---- pre-kernel: build swizzled per-tile images (grid 256 x 256) ----
__global__ void prep_kernel(const float* __restrict__ keys, f16* __restrict__ ws) {
  int i = blockIdx.x * 256 + threadIdx.x;  // 0..65535
  int t = i >> 10;
  {  // Kh image: key kk, chunk c; slot = c ^ ((kk&3)|(((kk>>3)&1)<<2))
    int kk = (i >> 5) & 31, c = i & 31;
    const float* src = keys + (((t << 5) + kk) << 8) + (c << 3);
    f16x8 v;
    #pragma unroll
    for (int e = 0; e < 8; ++e) v[e] = (f16)src[e];
    int xk = (kk & 3) | (((kk >> 3) & 1) << 2);
    *(f16x8*)&ws[t * 8192 + kk * 256 + ((c ^ xk) << 3)] = v;
  }
  {  // KT image: dim d, key-group g (keys g*8..g*8+7 at dim d), swizzled slot
    int d = (i >> 2) & 255, g = i & 3;
    const float* src = keys + (((t << 5) + (g << 3)) << 8) + d;
    f16x8 v;
    #pragma unroll
    for (int j = 0; j < 8; ++j) v[j] = (f16)src[j << 8];
    *(f16x8*)&ws[524288 + t * 8192 + (d >> 1) * 64 +
                 (((((d & 1) << 2) | g) ^ ((d >> 1) & 7)) << 3)] = v;
  }
}

__global__ __launch_bounds__(256, 2)
void mtr_kernel(const f16* __restrict__ ws,
                const float* __restrict__ query,
                float* __restrict__ out) {
  __shared__ f16 KB[2][8192];   // 32 KB: Kh images (dbuf)
  __shared__ f16 KT[2][8192];   // 32 KB: KT images (dbuf)

  const int tid  = threadIdx.x;
  const int lane = tid & 63;
  const int wave = tid >> 6;   // 0..3, owns q-rows [wave*16, wave*16+16)
  const int g    = lane >> 4;  // 0..3
  const int qr   = lane & 15;

  const int nbase  = blockIdx.x * 64;
  const int b      = nbase >> 12;
  const int hwbase = nbase & 4095;

  // ---- q fragments (fp16). Score B-layout: lane holds
  // q[row=qr][d = dt*32 + g*8 + j]
  f16x8 qh[8];
  {
    const float* qb = query + ((size_t)b << 20) + hwbase + wave * 16 + qr;
    #pragma unroll
    for (int dt = 0; dt < 8; ++dt)
      #pragma unroll
      for (int j = 0; j < 8; ++j) {
        int c = dt * 32 + g * 8 + j;
        qh[dt][j] = (f16)qb[(size_t)c << 12];
      }
  }

  f32x4 O[16];
  #pragma unroll
  for (int i = 0; i < 16; ++i) O[i] = (f32x4){0.f, 0.f, 0.f, 0.f};
  float m_run = -INFINITY;  // row-uniform (only updated via row-max path)
  float l_run = 0.f;        // PER-LANE partial; reduced in epilogue

  // score A-rows: key-permuted phys key = 8*(qr>>2) + 4*kt + (qr&3)
  const int rb0 = (((qr >> 2) << 3) + (qr & 3)) << 8;  // row pk0 (512B rows)
  const int rb1 = rb0 + 1024;                          // pk0 + 4
  const int xs  = (qr & 3) | (((qr >> 2) & 1) << 2);   // image xor, both rows
  // PV read row-base (f16 units) within each dtile's 1KB
  const int rbT = ((qr >> 1) << 6) + (((((qr & 1) << 2) | g) ^ ((qr >> 1) & 7)) << 3);

  // ---- DMA duty: waves 0,1 -> KB halves; waves 2,3 -> KT halves.
  const f16* wsrc = ws + ((wave >> 1) ? 524288 : 0) + ((wave & 1) << 12) + lane * 8;
  const int dst_half = (wave & 1) << 12;  // f16 offset of this wave's half

  // prologue: stage tile 0 into buffer 0
  {
    f16* dstb = ((wave >> 1) ? &KT[0][0] : &KB[0][0]) + dst_half;
    #pragma unroll
    for (int i = 0; i < 8; ++i) gl_lds16(wsrc + i * 512, dstb + i * 512);
  }
  __syncthreads();

  for (int t = 0; t < NT; ++t) {
    const int cur = t & 1;

    // ---- issue next-tile DMA into other buffer (drained by end barrier)
    if (t + 1 < NT) {
      f16* dstb = ((wave >> 1) ? &KT[cur ^ 1][0] : &KB[cur ^ 1][0]) + dst_half;
      const f16* s = wsrc + (t + 1) * 8192;
      #pragma unroll
      for (int i = 0; i < 8; ++i) gl_lds16(s + i * 512, dstb + i * 512);
    }

    // ---- score: S^T[key'][q], key-permuted A-rows, single term Kh*qh
    const f16* KBc = &KB[cur][0];
    f32x4 s0 = (f32x4){0.f, 0.f, 0.f, 0.f};
    f32x4 s1 = (f32x4){0.f, 0.f, 0.f, 0.f};
    #pragma unroll
    for (int dt = 0; dt < 8; ++dt) {
      int c = (dt << 2) + g;
      f16x8 a0 = *(const f16x8*)&KBc[rb0 + ((c ^ xs) << 3)];
      f16x8 a1 = *(const f16x8*)&KBc[rb1 + ((c ^ xs) << 3)];
      s0 = MF32(a0, qh[dt], s0);
      s1 = MF32(a1, qh[dt], s1);
    }
    // lane holds S[q=qr][key 8g+i] (s0) and 8g+4+i (s1)

    // ---- online softmax: zero cross-lane ops in common path
    float lmax = fmaxf(fmaxf(fmaxf(s0[0], s0[1]), fmaxf(s0[2], s0[3])),
                       fmaxf(fmaxf(s1[0], s1[1]), fmaxf(s1[2], s1[3])));

    if (__any(lmax > m_run + 8.f)) {  // identical semantics to row-max test
      float tmax = fmaxf(lmax, __shfl_xor(lmax, 16));
      tmax = fmaxf(tmax, __shfl_xor(tmax, 32));  // row max, row-uniform
      float m_new = fmaxf(m_run, tmax);
      float sc = __expf(m_run - m_new);  // row-uniform
      l_run *= sc;
      m_run = m_new;
      float osc0 = __shfl(sc, g * 4 + 0);
      float osc1 = __shfl(sc, g * 4 + 1);
      float osc2 = __shfl(sc, g * 4 + 2);
      float osc3 = __shfl(sc, g * 4 + 3);
      #pragma unroll
      for (int dtile = 0; dtile < 16; ++dtile) {
        O[dtile][0] *= osc0; O[dtile][1] *= osc1;
        O[dtile][2] *= osc2; O[dtile][3] *= osc3;
      }
    }

    float ts = 0.f;
    f16x8 pa;  // x32 PV A-frag: k = g*8+j -> phys key 8g+j
    #pragma unroll
    for (int i = 0; i < 4; ++i) {
      float e0 = __expf(s0[i] - m_run);
      float e1 = __expf(s1[i] - m_run);
      ts += e0 + e1;
      pa[i] = (f16)e0;
      pa[4 + i] = (f16)e1;
    }
    l_run += ts;  // per-lane partial (8 of this row's 32 keys this tile)

    // ---- PV: all-x32, B-frags from KT image (compile-time strides)
    const f16* KTc = &KT[cur][0];
    #pragma unroll
    for (int dtile = 0; dtile < 16; ++dtile) {
      f16x8 vb = *(const f16x8*)&KTc[dtile * 512 + rbT];
      O[dtile] = MF32(pa, vb, O[dtile]);
    }

    __syncthreads();  // next-tile images complete; buffers swap
  }

  // ---- epilogue: reduce row-sum across the row's 4 lanes, store NCHW
  l_run += __shfl_xor(l_run, 16);
  l_run += __shfl_xor(l_run, 32);  // row total on all 4 lanes of the row
  float n0 = 1.f / __shfl(l_run, g * 4 + 0);
  float n1 = 1.f / __shfl(l_run, g * 4 + 1);
  float n2 = 1.f / __shfl(l_run, g * 4 + 2);
  float n3 = 1.f / __shfl(l_run, g * 4 + 3);
  float* ob = out + ((size_t)b << 20) + hwbase + wave * 16 + g * 4;
  #pragma unroll
  for (int dtile = 0; dtile < 16; ++dtile) {
    int c = dtile * 16 + qr;
    float4 w4;
    w4.x = O[dtile][0] * n0;
    w4.y = O[dtile][1] * n1;
    w4.z = O[dtile][2] * n2;
    w4.w = O[dtile][3] * n3;
    *(float4*)(ob + ((size_t)c << 12)) = w4;
  }
}

extern "C" void kernel_launch(void* const* d_in, const int* in_sizes, int n_in,
                              void* d_out, int out_size, void* d_ws, size_t ws_size,
                              hipStream_t stream) {
  const float* keys  = (const float*)d_in[0];
  const float* query = (const float*)d_in[1];
  float* out = (float*)d_out;
  f16* ws = (f16*)d_ws;
  hipLaunchKernelGGL(prep_kernel, dim3(256), dim3(256), 0, stream, keys, ws);
  hipLaunchKernelGGL(mtr_kernel, dim3(512), dim3(256), 0, stream, ws, query, out);
}

// Round 13
// 103.161 us; speedup vs baseline: 1.5415x; 1.0156x over previous
//
#include <hip/hip_runtime.h>

// out = softmax(q @ keys^T) @ keys, fused flash-style, round 13.
// = r12 (104.8us) with ONE change: one 512-thread block per CU (grid 256,
//   8 waves, 128 q-rows) instead of two 256-thread blocks -> each K-tile is
//   DMA-staged ONCE per CU (32 KB/tile, was 64 KB). DS-pipe work/CU/tile:
//   228k -> 212k cyc. FETCH should halve (tile images read once per CU).
//   Per-wave dataflow, swizzles, softmax, epilogue byte-identical to r12.

typedef _Float16 f16;
typedef f16 f16x8 __attribute__((ext_vector_type(8)));
typedef float f32x4 __attribute__((ext_vector_type(4)));

#define NT 64
#define MF32(a, b, c) __builtin_amdgcn_mfma_f32_16x16x32_f16(a, b, c, 0, 0, 0)

__device__ __forceinline__ void gl_lds16(const f16* g, f16* l) {
  __builtin_amdgcn_global_load_lds(
      (const __attribute__((address_space(1))) void*)g,
      (__attribute__((address_space(3))) void*)l, 16, 0, 0);
}

// ---- pre-kernel: build swizzled per-tile images (grid 256 x 256) ----
__global__ void prep_kernel(const float* __restrict__ keys, f16* __restrict__ ws) {
  int i = blockIdx.x * 256 + threadIdx.x;  // 0..65535
  int t = i >> 10;
  {  // Kh image: key kk, chunk c; slot = c ^ ((kk&3)|(((kk>>3)&1)<<2))
    int kk = (i >> 5) & 31, c = i & 31;
    const float* src = keys + (((t << 5) + kk) << 8) + (c << 3);
    f16x8 v;
    #pragma unroll
    for (int e = 0; e < 8; ++e) v[e] = (f16)src[e];
    int xk = (kk & 3) | (((kk >> 3) & 1) << 2);
    *(f16x8*)&ws[t * 8192 + kk * 256 + ((c ^ xk) << 3)] = v;
  }
  {  // KT image: dim d, key-group g (keys g*8..g*8+7 at dim d), swizzled slot
    int d = (i >> 2) & 255, g = i & 3;
    const float* src = keys + (((t << 5) + (g << 3)) << 8) + d;
    f16x8 v;
    #pragma unroll
    for (int j = 0; j < 8; ++j) v[j] = (f16)src[j << 8];
    *(f16x8*)&ws[524288 + t * 8192 + (d >> 1) * 64 +
                 (((((d & 1) << 2) | g) ^ ((d >> 1) & 7)) << 3)] = v;
  }
}

__global__ __launch_bounds__(512, 1)
void mtr_kernel(const f16* __restrict__ ws,
                const float* __restrict__ query,
                float* __restrict__ out) {
  __shared__ f16 KB[2][8192];   // 32 KB: Kh images (dbuf)
  __shared__ f16 KT[2][8192];   // 32 KB: KT images (dbuf)

  const int tid  = threadIdx.x;
  const int lane = tid & 63;
  const int wave = tid >> 6;   // 0..7, owns q-rows [wave*16, wave*16+16)
  const int g    = lane >> 4;  // 0..3
  const int qr   = lane & 15;

  const int nbase  = blockIdx.x * 128;  // grid 256, 128 q-rows/block
  const int b      = nbase >> 12;
  const int hwbase = nbase & 4095;

  // ---- q fragments (fp16). Score B-layout: lane holds
  // q[row=qr][d = dt*32 + g*8 + j]
  f16x8 qh[8];
  {
    const float* qb = query + ((size_t)b << 20) + hwbase + wave * 16 + qr;
    #pragma unroll
    for (int dt = 0; dt < 8; ++dt)
      #pragma unroll
      for (int j = 0; j < 8; ++j) {
        int c = dt * 32 + g * 8 + j;
        qh[dt][j] = (f16)qb[(size_t)c << 12];
      }
  }

  f32x4 O[16];
  #pragma unroll
  for (int i = 0; i < 16; ++i) O[i] = (f32x4){0.f, 0.f, 0.f, 0.f};
  float m_run = -INFINITY;  // row-uniform (only updated via row-max path)
  float l_run = 0.f;        // PER-LANE partial; reduced in epilogue

  // score A-rows: key-permuted phys key = 8*(qr>>2) + 4*kt + (qr&3)
  const int rb0 = (((qr >> 2) << 3) + (qr & 3)) << 8;  // row pk0 (512B rows)
  const int rb1 = rb0 + 1024;                          // pk0 + 4
  const int xs  = (qr & 3) | (((qr >> 2) & 1) << 2);   // image xor, both rows
  // PV read row-base (f16 units) within each dtile's 1KB
  const int rbT = ((qr >> 1) << 6) + (((((qr & 1) << 2) | g) ^ ((qr >> 1) & 7)) << 3);

  // ---- DMA duty: waves 0-3 -> KB quarters; waves 4-7 -> KT quarters.
  // 4 KB (4 x 1KB gl_lds16) per wave per tile; tile staged ONCE per CU.
  const f16* wsrc = ws + ((wave >> 2) ? 524288 : 0) + ((wave & 3) << 11) + lane * 8;
  const int dst_q = (wave & 3) << 11;  // f16 offset of this wave's quarter

  // prologue: stage tile 0 into buffer 0
  {
    f16* dstb = ((wave >> 2) ? &KT[0][0] : &KB[0][0]) + dst_q;
    #pragma unroll
    for (int i = 0; i < 4; ++i) gl_lds16(wsrc + i * 512, dstb + i * 512);
  }
  __syncthreads();

  for (int t = 0; t < NT; ++t) {
    const int cur = t & 1;

    // ---- issue next-tile DMA into other buffer (drained by end barrier)
    if (t + 1 < NT) {
      f16* dstb = ((wave >> 2) ? &KT[cur ^ 1][0] : &KB[cur ^ 1][0]) + dst_q;
      const f16* s = wsrc + (t + 1) * 8192;
      #pragma unroll
      for (int i = 0; i < 4; ++i) gl_lds16(s + i * 512, dstb + i * 512);
    }

    // ---- score: S^T[key'][q], key-permuted A-rows, single term Kh*qh
    const f16* KBc = &KB[cur][0];
    f32x4 s0 = (f32x4){0.f, 0.f, 0.f, 0.f};
    f32x4 s1 = (f32x4){0.f, 0.f, 0.f, 0.f};
    #pragma unroll
    for (int dt = 0; dt < 8; ++dt) {
      int c = (dt << 2) + g;
      f16x8 a0 = *(const f16x8*)&KBc[rb0 + ((c ^ xs) << 3)];
      f16x8 a1 = *(const f16x8*)&KBc[rb1 + ((c ^ xs) << 3)];
      s0 = MF32(a0, qh[dt], s0);
      s1 = MF32(a1, qh[dt], s1);
    }
    // lane holds S[q=qr][key 8g+i] (s0) and 8g+4+i (s1)

    // ---- online softmax: zero cross-lane ops in common path
    float lmax = fmaxf(fmaxf(fmaxf(s0[0], s0[1]), fmaxf(s0[2], s0[3])),
                       fmaxf(fmaxf(s1[0], s1[1]), fmaxf(s1[2], s1[3])));

    if (__any(lmax > m_run + 8.f)) {  // identical semantics to row-max test
      float tmax = fmaxf(lmax, __shfl_xor(lmax, 16));
      tmax = fmaxf(tmax, __shfl_xor(tmax, 32));  // row max, row-uniform
      float m_new = fmaxf(m_run, tmax);
      float sc = __expf(m_run - m_new);  // row-uniform
      l_run *= sc;
      m_run = m_new;
      float osc0 = __shfl(sc, g * 4 + 0);
      float osc1 = __shfl(sc, g * 4 + 1);
      float osc2 = __shfl(sc, g * 4 + 2);
      float osc3 = __shfl(sc, g * 4 + 3);
      #pragma unroll
      for (int dtile = 0; dtile < 16; ++dtile) {
        O[dtile][0] *= osc0; O[dtile][1] *= osc1;
        O[dtile][2] *= osc2; O[dtile][3] *= osc3;
      }
    }

    float ts = 0.f;
    f16x8 pa;  // x32 PV A-frag: k = g*8+j -> phys key 8g+j
    #pragma unroll
    for (int i = 0; i < 4; ++i) {
      float e0 = __expf(s0[i] - m_run);
      float e1 = __expf(s1[i] - m_run);
      ts += e0 + e1;
      pa[i] = (f16)e0;
      pa[4 + i] = (f16)e1;
    }
    l_run += ts;  // per-lane partial (8 of this row's 32 keys this tile)

    // ---- PV: all-x32, B-frags from KT image (compile-time strides)
    const f16* KTc = &KT[cur][0];
    #pragma unroll
    for (int dtile = 0; dtile < 16; ++dtile) {
      f16x8 vb = *(const f16x8*)&KTc[dtile * 512 + rbT];
      O[dtile] = MF32(pa, vb, O[dtile]);
    }

    __syncthreads();  // next-tile images complete; buffers swap
  }

  // ---- epilogue: reduce row-sum across the row's 4 lanes, store NCHW
  l_run += __shfl_xor(l_run, 16);
  l_run += __shfl_xor(l_run, 32);  // row total on all 4 lanes of the row
  float n0 = 1.f / __shfl(l_run, g * 4 + 0);
  float n1 = 1.f / __shfl(l_run, g * 4 + 1);
  float n2 = 1.f / __shfl(l_run, g * 4 + 2);
  float n3 = 1.f / __shfl(l_run, g * 4 + 3);
  float* ob = out + ((size_t)b << 20) + hwbase + wave * 16 + g * 4;
  #pragma unroll
  for (int dtile = 0; dtile < 16; ++dtile) {
    int c = dtile * 16 + qr;
    float4 w4;
    w4.x = O[dtile][0] * n0;
    w4.y = O[dtile][1] * n1;
    w4.z = O[dtile][2] * n2;
    w4.w = O[dtile][3] * n3;
    *(float4*)(ob + ((size_t)c << 12)) = w4;
  }
}

extern "C" void kernel_launch(void* const* d_in, const int* in_sizes, int n_in,
                              void* d_out, int out_size, void* d_ws, size_t ws_size,
                              hipStream_t stream) {
  const float* keys  = (const float*)d_in[0];
  const float* query = (const float*)d_in[1];
  float* out = (float*)d_out;
  f16* ws = (f16*)d_ws;
  hipLaunchKernelGGL(prep_kernel, dim3(256), dim3(256), 0, stream, keys, ws);
  hipLaunchKernelGGL(mtr_kernel, dim3(256), dim3(512), 0, stream, ws, query, out);
}